// Round 6
// baseline (1458.794 us; speedup 1.0000x reference)
//
#include <hip/hip_runtime.h>

// EllipticGNN: 2-layer GCN + linear head, f32.
// Slice-major feature layout [16 slices][N][8 floats]; XCD-pinned slices so
// the random gather is L2-resident. Dense tail does W2 GEMM + head.

constexpr int NN   = 100000;
constexpr int NE   = 1600000;
constexpr int FIN  = 165;
constexpr int HID  = 128;
constexpr int SLW  = 8;                 // slice width (floats)
constexpr int SLICES = HID / SLW;       // 16
constexpr int NB_AGG = NN / 16;         // 6250 chunks of 16 nodes

__global__ __launch_bounds__(256) void k_zero_counts(int* __restrict__ c) {
    int i = blockIdx.x * 256 + threadIdx.x;
    if (i < NN) c[i] = 0;
}

__global__ __launch_bounds__(256) void k_hist(const int* __restrict__ dst,
                                              int* __restrict__ c) {
    int i = blockIdx.x * 256 + threadIdx.x;
    if (i < NE) atomicAdd(&c[dst[i]], 1);
}

__global__ __launch_bounds__(256) void k_dinv(const int* __restrict__ c,
                                              float* __restrict__ dinv) {
    int i = blockIdx.x * 256 + threadIdx.x;
    if (i < NN) dinv[i] = rsqrtf((float)c[i] + 1.0f);   // +1 self-loop
}

__global__ __launch_bounds__(256) void k_scanA(const int* __restrict__ c,
                                               int* __restrict__ rowptr,
                                               int* __restrict__ bsum) {
    __shared__ int s[256];
    int t = threadIdx.x;
    int i = blockIdx.x * 256 + t;
    int v = (i < NN) ? c[i] : 0;
    s[t] = v; __syncthreads();
    for (int off = 1; off < 256; off <<= 1) {
        int add = (t >= off) ? s[t - off] : 0;
        __syncthreads();
        s[t] += add;
        __syncthreads();
    }
    if (i < NN) rowptr[i] = s[t] - v;
    if (t == 255) bsum[blockIdx.x] = s[255];
}

__global__ __launch_bounds__(512) void k_scanB(int* __restrict__ bsum, int nb) {
    __shared__ int s[512];
    int t = threadIdx.x;
    int v = (t < nb) ? bsum[t] : 0;
    s[t] = v; __syncthreads();
    for (int off = 1; off < 512; off <<= 1) {
        int add = (t >= off) ? s[t - off] : 0;
        __syncthreads();
        s[t] += add;
        __syncthreads();
    }
    if (t < nb) bsum[t] = s[t] - v;
}

__global__ __launch_bounds__(256) void k_scanC(int* __restrict__ rowptr,
                                               const int* __restrict__ bsum,
                                               int* __restrict__ c) {
    int i = blockIdx.x * 256 + threadIdx.x;
    if (i < NN) { rowptr[i] += bsum[blockIdx.x]; c[i] = 0; }
    if (i == 0) rowptr[NN] = NE;
}

__global__ __launch_bounds__(256) void k_fill(const int* __restrict__ src,
                                              const int* __restrict__ dst,
                                              const int* __restrict__ rowptr,
                                              int* __restrict__ cur,
                                              int* __restrict__ col) {
    int e = blockIdx.x * 256 + threadIdx.x;
    if (e >= NE) return;
    int s = src[e], d = dst[e];
    int pos = rowptr[d] + atomicAdd(&cur[d], 1);
    col[pos] = s;
}

// Tiled GEMM with slice-major output: Y[s][row][8], s = col/8.
template<int K, int KP, bool VEC4>
__global__ __launch_bounds__(256) void k_gemm_sl(const float* __restrict__ X,
                                                 const float* __restrict__ W,
                                                 float* __restrict__ Y) {
    __shared__ float Xs[64 * KP];
    const int tid = threadIdx.x;
    const long base = (long)blockIdx.x * 64;
    const int rows = (NN - base < 64) ? (int)(NN - base) : 64;

    if (VEC4) {
        const float4* Xg = (const float4*)(X + base * K);
        const int tot4 = rows * (K / 4);
        for (int i = tid; i < tot4; i += 256) {
            int r = i / (K / 4), c4 = i % (K / 4);
            *(float4*)&Xs[r * KP + c4 * 4] = Xg[i];
        }
    } else {
        const int tot = rows * K;
        const float* Xg = X + base * K;
        for (int i = tid; i < tot; i += 256) {
            int r = i / K, c = i % K;
            Xs[r * KP + c] = Xg[i];
        }
    }
    __syncthreads();

    const int cg = tid & 31;
    const int rg = tid >> 5;
    const float* Wp = W + 4 * cg;
    const float* Xrow = &Xs[rg * 8 * KP];

    float acc[8][4];
#pragma unroll
    for (int r = 0; r < 8; ++r)
#pragma unroll
        for (int c = 0; c < 4; ++c) acc[r][c] = 0.0f;

    int k = 0;
    for (; k + 4 <= K; k += 4) {
        float4 w0 = *(const float4*)(Wp + (k + 0) * HID);
        float4 w1 = *(const float4*)(Wp + (k + 1) * HID);
        float4 w2 = *(const float4*)(Wp + (k + 2) * HID);
        float4 w3 = *(const float4*)(Wp + (k + 3) * HID);
#pragma unroll
        for (int r = 0; r < 8; ++r) {
            float4 xv = *(const float4*)&Xrow[r * KP + k];
            acc[r][0] += xv.x * w0.x + xv.y * w1.x + xv.z * w2.x + xv.w * w3.x;
            acc[r][1] += xv.x * w0.y + xv.y * w1.y + xv.z * w2.y + xv.w * w3.y;
            acc[r][2] += xv.x * w0.z + xv.y * w1.z + xv.z * w2.z + xv.w * w3.z;
            acc[r][3] += xv.x * w0.w + xv.y * w1.w + xv.z * w2.w + xv.w * w3.w;
        }
    }
    for (; k < K; ++k) {
        float4 wt = *(const float4*)(Wp + k * HID);
#pragma unroll
        for (int r = 0; r < 8; ++r) {
            float xs = Xrow[r * KP + k];
            acc[r][0] += xs * wt.x;
            acc[r][1] += xs * wt.y;
            acc[r][2] += xs * wt.z;
            acc[r][3] += xs * wt.w;
        }
    }

    const int slice = cg >> 1;
    const int off   = (cg & 1) * 4;
#pragma unroll
    for (int r = 0; r < 8; ++r) {
        long row = base + rg * 8 + r;
        if (row < NN) {
            float4 o = make_float4(acc[r][0], acc[r][1], acc[r][2], acc[r][3]);
            *(float4*)&Y[((size_t)slice * NN + row) * SLW + off] = o;
        }
    }
}

// Sliced aggregation: O[s][i][:] = dinv[i]*(H[s][i][:]*dinv[i] +
// sum_e dinv[col]*H[s][col][:]) (+bias, relu). Slice s pinned to XCD s/2
// via blockIdx%8 so H-slice (3.2 MB) stays L2-resident per XCD.
template<bool BIASRELU>
__global__ __launch_bounds__(256) void k_agg_sl(const float* __restrict__ Hs,
                                                const int* __restrict__ rowptr,
                                                const int* __restrict__ col,
                                                const float* __restrict__ dinv,
                                                const float* __restrict__ bias,
                                                float* __restrict__ Os) {
    const int b = blockIdx.x;
    const int x = b & 7;                     // presumed XCD id
    const int q = b >> 3;                    // 0 .. 2*NB_AGG-1
    const int second = (q >= NB_AGG);
    const int s = 2 * x + second;
    const int chunk = second ? q - NB_AGG : q;

    const int lane = threadIdx.x & 63;
    const int wvid = threadIdx.x >> 6;
    const int eSub = lane >> 3;              // 0..7: edge sub-lane
    const int c8   = lane & 7;               // col within slice

    const float* H = Hs + (size_t)s * NN * SLW;
    float*       O = Os + (size_t)s * NN * SLW;
    const float bval = BIASRELU ? bias[s * SLW + c8] : 0.0f;

#pragma unroll
    for (int n = 0; n < 4; ++n) {
        const int i = chunk * 16 + wvid * 4 + n;
        const float di = dinv[i];
        const int r0 = rowptr[i], r1 = rowptr[i + 1];
        float acc = 0.0f;
        for (int k = r0 + eSub; k < r1; k += 8) {
            int cs = __builtin_nontemporal_load(&col[k]);
            acc += dinv[cs] * H[(size_t)cs * SLW + c8];
        }
        acc += __shfl_xor(acc, 8);
        acc += __shfl_xor(acc, 16);
        acc += __shfl_xor(acc, 32);
        float self = H[(size_t)i * SLW + c8];
        float r = di * (self * di + acc);
        if (BIASRELU) r = fmaxf(r + bval, 0.0f);
        if (eSub == 0)
            __builtin_nontemporal_store(r, &O[(size_t)i * SLW + c8]);
    }
}

// Dense tail: out[i] = relu(g[i] @ W2 + b2) @ W3 + b3, g in slice layout.
__global__ __launch_bounds__(256) void k_tail(const float* __restrict__ Gs,
                                              const float* __restrict__ W2,
                                              const float* __restrict__ b2,
                                              const float* __restrict__ W3,
                                              const float* __restrict__ b3,
                                              float* __restrict__ out) {
    __shared__ float Xs[64 * 132];
    const int tid = threadIdx.x;
    const long base = (long)blockIdx.x * 64;

    for (int t = tid; t < 2048; t += 256) {        // 64 rows x 32 float4
        int n = t >> 5;
        int q = t & 31;
        int s = q >> 1, off = (q & 1) * 4;
        long row = base + n;
        float4 v = make_float4(0.f, 0.f, 0.f, 0.f);
        if (row < NN)
            v = *(const float4*)&Gs[((size_t)s * NN + row) * SLW + off];
        *(float4*)&Xs[n * 132 + q * 4] = v;
    }
    __syncthreads();

    const int cg = tid & 31;
    const int rg = tid >> 5;
    const float* Wp = W2 + 4 * cg;
    const float* Xrow = &Xs[rg * 8 * 132];

    float acc[8][4];
#pragma unroll
    for (int r = 0; r < 8; ++r)
#pragma unroll
        for (int c = 0; c < 4; ++c) acc[r][c] = 0.0f;

    for (int k = 0; k < HID; k += 4) {
        float4 w0 = *(const float4*)(Wp + (k + 0) * HID);
        float4 w1 = *(const float4*)(Wp + (k + 1) * HID);
        float4 w2 = *(const float4*)(Wp + (k + 2) * HID);
        float4 w3 = *(const float4*)(Wp + (k + 3) * HID);
#pragma unroll
        for (int r = 0; r < 8; ++r) {
            float4 xv = *(const float4*)&Xrow[r * 132 + k];
            acc[r][0] += xv.x * w0.x + xv.y * w1.x + xv.z * w2.x + xv.w * w3.x;
            acc[r][1] += xv.x * w0.y + xv.y * w1.y + xv.z * w2.y + xv.w * w3.y;
            acc[r][2] += xv.x * w0.z + xv.y * w1.z + xv.z * w2.z + xv.w * w3.z;
            acc[r][3] += xv.x * w0.w + xv.y * w1.w + xv.z * w2.w + xv.w * w3.w;
        }
    }

    const float4 bb = *(const float4*)&b2[4 * cg];
    float2 w3v[4];
#pragma unroll
    for (int c = 0; c < 4; ++c)
        w3v[c] = *(const float2*)&W3[(4 * cg + c) * 2];
    const float b30 = b3[0], b31 = b3[1];

#pragma unroll
    for (int r = 0; r < 8; ++r) {
        float h0 = fmaxf(acc[r][0] + bb.x, 0.f);
        float h1 = fmaxf(acc[r][1] + bb.y, 0.f);
        float h2 = fmaxf(acc[r][2] + bb.z, 0.f);
        float h3 = fmaxf(acc[r][3] + bb.w, 0.f);
        float p0 = h0 * w3v[0].x + h1 * w3v[1].x + h2 * w3v[2].x + h3 * w3v[3].x;
        float p1 = h0 * w3v[0].y + h1 * w3v[1].y + h2 * w3v[2].y + h3 * w3v[3].y;
#pragma unroll
        for (int m = 1; m < 32; m <<= 1) {
            p0 += __shfl_xor(p0, m);
            p1 += __shfl_xor(p1, m);
        }
        long row = base + rg * 8 + r;
        if (cg == 0 && row < NN)
            ((float2*)out)[row] = make_float2(p0 + b30, p1 + b31);
    }
}

extern "C" void kernel_launch(void* const* d_in, const int* in_sizes, int n_in,
                              void* d_out, int out_size, void* d_ws, size_t ws_size,
                              hipStream_t stream) {
    const float* x   = (const float*)d_in[0];
    const int*   ei  = (const int*)d_in[1];
    const float* W1  = (const float*)d_in[2];
    const float* b1  = (const float*)d_in[3];
    const float* W2  = (const float*)d_in[4];
    const float* b2  = (const float*)d_in[5];
    const float* W3  = (const float*)d_in[6];
    const float* b3  = (const float*)d_in[7];
    float* out = (float*)d_out;

    const int* srcA = ei;
    const int* dstA = ei + NE;

    char* p = (char*)d_ws;
    auto alloc = [&](size_t bytes) {
        char* r = p;
        p += (bytes + 255) & ~(size_t)255;
        return r;
    };
    float* dinv   = (float*)alloc(NN * 4);
    int*   counts = (int*)  alloc(NN * 4);
    int*   rowptr = (int*)  alloc((NN + 1) * 4);
    int*   bsum   = (int*)  alloc(512 * 4);
    int*   col    = (int*)  alloc((size_t)NE * 4);
    float* bufA   = (float*)alloc((size_t)NN * HID * 4);   // h1, then g
    float* bufB   = (float*)alloc((size_t)NN * HID * 4);   // h2

    const int nb_n = (NN + 255) / 256;
    const int nb_e = (NE + 255) / 256;
    const int nb_g = (NN + 63) / 64;

    // ---- CSR build ----
    k_zero_counts<<<nb_n, 256, 0, stream>>>(counts);
    k_hist<<<nb_e, 256, 0, stream>>>(dstA, counts);
    k_dinv<<<nb_n, 256, 0, stream>>>(counts, dinv);
    k_scanA<<<nb_n, 256, 0, stream>>>(counts, rowptr, bsum);
    k_scanB<<<1, 512, 0, stream>>>(bsum, nb_n);
    k_scanC<<<nb_n, 256, 0, stream>>>(rowptr, bsum, counts);
    k_fill<<<nb_e, 256, 0, stream>>>(srcA, dstA, rowptr, counts, col);

    // ---- layer 1 GEMM -> h1 (sliced) ----
    k_gemm_sl<FIN, 168, false><<<nb_g, 256, 0, stream>>>(x, W1, bufA);

    // ---- agg1 + b1 + relu -> h2 (sliced) ----
    k_agg_sl<true><<<SLICES * NB_AGG, 256, 0, stream>>>(bufA, rowptr, col,
                                                        dinv, b1, bufB);

    // ---- agg2 (pure A-hat) -> g (sliced) ----
    k_agg_sl<false><<<SLICES * NB_AGG, 256, 0, stream>>>(bufB, rowptr, col,
                                                         dinv, nullptr, bufA);

    // ---- tail: relu(g @ W2 + b2) @ W3 + b3 ----
    k_tail<<<nb_g, 256, 0, stream>>>(bufA, W2, b2, W3, b3, out);
}

// Round 7
// 1105.859 us; speedup vs baseline: 1.3191x; 1.3191x over previous
//
#include <hip/hip_runtime.h>

// EllipticGNN: 2-layer GCN + linear head, f32.
// Slice-major feature layout [16 slices][N][8 floats]; XCD-pinned slices keep
// the random gather L2-resident. Agg engine: 4-lane groups, one node per
// group, edge loop unrolled x4. Dense tail does W2 GEMM + head.

constexpr int NN   = 100000;
constexpr int NE   = 1600000;
constexpr int FIN  = 165;
constexpr int HID  = 128;
constexpr int SLW  = 8;                 // slice width (floats)
constexpr int SLICES = HID / SLW;       // 16
constexpr int CHUNKS = (NN + 63) / 64;  // 1563 chunks of 64 nodes

__global__ __launch_bounds__(256) void k_zero_counts(int* __restrict__ c) {
    int i = blockIdx.x * 256 + threadIdx.x;
    if (i < NN) c[i] = 0;
}

__global__ __launch_bounds__(256) void k_hist(const int* __restrict__ dst,
                                              int* __restrict__ c) {
    int i = blockIdx.x * 256 + threadIdx.x;
    if (i < NE) atomicAdd(&c[dst[i]], 1);
}

__global__ __launch_bounds__(256) void k_dinv(const int* __restrict__ c,
                                              float* __restrict__ dinv) {
    int i = blockIdx.x * 256 + threadIdx.x;
    if (i < NN) dinv[i] = rsqrtf((float)c[i] + 1.0f);   // +1 self-loop
}

__global__ __launch_bounds__(256) void k_scanA(const int* __restrict__ c,
                                               int* __restrict__ rowptr,
                                               int* __restrict__ bsum) {
    __shared__ int s[256];
    int t = threadIdx.x;
    int i = blockIdx.x * 256 + t;
    int v = (i < NN) ? c[i] : 0;
    s[t] = v; __syncthreads();
    for (int off = 1; off < 256; off <<= 1) {
        int add = (t >= off) ? s[t - off] : 0;
        __syncthreads();
        s[t] += add;
        __syncthreads();
    }
    if (i < NN) rowptr[i] = s[t] - v;
    if (t == 255) bsum[blockIdx.x] = s[255];
}

__global__ __launch_bounds__(512) void k_scanB(int* __restrict__ bsum, int nb) {
    __shared__ int s[512];
    int t = threadIdx.x;
    int v = (t < nb) ? bsum[t] : 0;
    s[t] = v; __syncthreads();
    for (int off = 1; off < 512; off <<= 1) {
        int add = (t >= off) ? s[t - off] : 0;
        __syncthreads();
        s[t] += add;
        __syncthreads();
    }
    if (t < nb) bsum[t] = s[t] - v;
}

__global__ __launch_bounds__(256) void k_scanC(int* __restrict__ rowptr,
                                               const int* __restrict__ bsum,
                                               int* __restrict__ c) {
    int i = blockIdx.x * 256 + threadIdx.x;
    if (i < NN) { rowptr[i] += bsum[blockIdx.x]; c[i] = 0; }
    if (i == 0) rowptr[NN] = NE;
}

__global__ __launch_bounds__(256) void k_fill(const int* __restrict__ src,
                                              const int* __restrict__ dst,
                                              const int* __restrict__ rowptr,
                                              int* __restrict__ cur,
                                              int* __restrict__ col) {
    int e = blockIdx.x * 256 + threadIdx.x;
    if (e >= NE) return;
    int s = src[e], d = dst[e];
    int pos = rowptr[d] + atomicAdd(&cur[d], 1);
    col[pos] = s;
}

// Tiled GEMM with slice-major output: Y[s][row][8], s = col/8.
template<int K, int KP, bool VEC4>
__global__ __launch_bounds__(256) void k_gemm_sl(const float* __restrict__ X,
                                                 const float* __restrict__ W,
                                                 float* __restrict__ Y) {
    __shared__ float Xs[64 * KP];
    const int tid = threadIdx.x;
    const long base = (long)blockIdx.x * 64;
    const int rows = (NN - base < 64) ? (int)(NN - base) : 64;

    if (VEC4) {
        const float4* Xg = (const float4*)(X + base * K);
        const int tot4 = rows * (K / 4);
        for (int i = tid; i < tot4; i += 256) {
            int r = i / (K / 4), c4 = i % (K / 4);
            *(float4*)&Xs[r * KP + c4 * 4] = Xg[i];
        }
    } else {
        const int tot = rows * K;
        const float* Xg = X + base * K;
        for (int i = tid; i < tot; i += 256) {
            int r = i / K, c = i % K;
            Xs[r * KP + c] = Xg[i];
        }
    }
    __syncthreads();

    const int cg = tid & 31;
    const int rg = tid >> 5;
    const float* Wp = W + 4 * cg;
    const float* Xrow = &Xs[rg * 8 * KP];

    float acc[8][4];
#pragma unroll
    for (int r = 0; r < 8; ++r)
#pragma unroll
        for (int c = 0; c < 4; ++c) acc[r][c] = 0.0f;

    int k = 0;
    for (; k + 4 <= K; k += 4) {
        float4 w0 = *(const float4*)(Wp + (k + 0) * HID);
        float4 w1 = *(const float4*)(Wp + (k + 1) * HID);
        float4 w2 = *(const float4*)(Wp + (k + 2) * HID);
        float4 w3 = *(const float4*)(Wp + (k + 3) * HID);
#pragma unroll
        for (int r = 0; r < 8; ++r) {
            float4 xv = *(const float4*)&Xrow[r * KP + k];
            acc[r][0] += xv.x * w0.x + xv.y * w1.x + xv.z * w2.x + xv.w * w3.x;
            acc[r][1] += xv.x * w0.y + xv.y * w1.y + xv.z * w2.y + xv.w * w3.y;
            acc[r][2] += xv.x * w0.z + xv.y * w1.z + xv.z * w2.z + xv.w * w3.z;
            acc[r][3] += xv.x * w0.w + xv.y * w1.w + xv.z * w2.w + xv.w * w3.w;
        }
    }
    for (; k < K; ++k) {
        float4 wt = *(const float4*)(Wp + k * HID);
#pragma unroll
        for (int r = 0; r < 8; ++r) {
            float xs = Xrow[r * KP + k];
            acc[r][0] += xs * wt.x;
            acc[r][1] += xs * wt.y;
            acc[r][2] += xs * wt.z;
            acc[r][3] += xs * wt.w;
        }
    }

    const int slice = cg >> 1;
    const int off   = (cg & 1) * 4;
#pragma unroll
    for (int r = 0; r < 8; ++r) {
        long row = base + rg * 8 + r;
        if (row < NN) {
            float4 o = make_float4(acc[r][0], acc[r][1], acc[r][2], acc[r][3]);
            *(float4*)&Y[((size_t)slice * NN + row) * SLW + off] = o;
        }
    }
}

// Sliced aggregation, 4-lane groups. Group g of a block owns node
// i = chunk*64 + g; lane c4 owns cols {2c4, 2c4+1} of the 8-wide slice.
// Slice s pinned to XCD s&7 via blockIdx&7; col loads nontemporal so the
// 3.2 MB slice + 400 KB dinv stay L2-resident.
template<bool BIASRELU>
__global__ __launch_bounds__(256) void k_agg_px(const float* __restrict__ Hs,
                                                const int* __restrict__ rowptr,
                                                const int* __restrict__ col,
                                                const float* __restrict__ dinv,
                                                const float* __restrict__ bias,
                                                float* __restrict__ Os) {
    const int b = blockIdx.x;
    const int x = b & 7;                    // presumed XCD id
    const int j = b >> 3;                   // 0 .. 2*CHUNKS-1
    const int second = (j >= CHUNKS);
    const int s = x + 8 * second;
    const int chunk = second ? j - CHUNKS : j;

    const int g  = threadIdx.x >> 2;        // group 0..63 -> node
    const int c4 = threadIdx.x & 3;         // float2 index within row

    const int i = chunk * 64 + g;
    if (i >= NN) return;

    const float2* H2 = (const float2*)(Hs + (size_t)s * NN * SLW);
    float2*       O2 = (float2*)      (Os + (size_t)s * NN * SLW);

    const float di = dinv[i];
    int k = rowptr[i];
    const int end = rowptr[i + 1];

    float2 self = H2[(size_t)i * 4 + c4];
    float a0 = self.x * di;
    float a1 = self.y * di;

    for (; k + 4 <= end; k += 4) {
        int c0 = __builtin_nontemporal_load(&col[k + 0]);
        int c1 = __builtin_nontemporal_load(&col[k + 1]);
        int c2 = __builtin_nontemporal_load(&col[k + 2]);
        int c3 = __builtin_nontemporal_load(&col[k + 3]);
        float w0 = dinv[c0], w1 = dinv[c1], w2 = dinv[c2], w3 = dinv[c3];
        float2 h0 = H2[(size_t)c0 * 4 + c4];
        float2 h1 = H2[(size_t)c1 * 4 + c4];
        float2 h2 = H2[(size_t)c2 * 4 + c4];
        float2 h3 = H2[(size_t)c3 * 4 + c4];
        a0 += w0 * h0.x + w1 * h1.x + w2 * h2.x + w3 * h3.x;
        a1 += w0 * h0.y + w1 * h1.y + w2 * h2.y + w3 * h3.y;
    }
    for (; k < end; ++k) {
        int cs = __builtin_nontemporal_load(&col[k]);
        float w = dinv[cs];
        float2 h = H2[(size_t)cs * 4 + c4];
        a0 += w * h.x;
        a1 += w * h.y;
    }

    float r0 = di * a0;
    float r1 = di * a1;
    if (BIASRELU) {
        const float2 bb = *(const float2*)&bias[s * SLW + 2 * c4];
        r0 = fmaxf(r0 + bb.x, 0.0f);
        r1 = fmaxf(r1 + bb.y, 0.0f);
    }
    O2[(size_t)i * 4 + c4] = make_float2(r0, r1);
}

// Dense tail: out[i] = relu(g[i] @ W2 + b2) @ W3 + b3, g in slice layout.
__global__ __launch_bounds__(256) void k_tail(const float* __restrict__ Gs,
                                              const float* __restrict__ W2,
                                              const float* __restrict__ b2,
                                              const float* __restrict__ W3,
                                              const float* __restrict__ b3,
                                              float* __restrict__ out) {
    __shared__ float Xs[64 * 132];
    const int tid = threadIdx.x;
    const long base = (long)blockIdx.x * 64;

    for (int t = tid; t < 2048; t += 256) {        // 64 rows x 32 float4
        int n = t >> 5;
        int q = t & 31;
        int s = q >> 1, off = (q & 1) * 4;
        long row = base + n;
        float4 v = make_float4(0.f, 0.f, 0.f, 0.f);
        if (row < NN)
            v = *(const float4*)&Gs[((size_t)s * NN + row) * SLW + off];
        *(float4*)&Xs[n * 132 + q * 4] = v;
    }
    __syncthreads();

    const int cg = tid & 31;
    const int rg = tid >> 5;
    const float* Wp = W2 + 4 * cg;
    const float* Xrow = &Xs[rg * 8 * 132];

    float acc[8][4];
#pragma unroll
    for (int r = 0; r < 8; ++r)
#pragma unroll
        for (int c = 0; c < 4; ++c) acc[r][c] = 0.0f;

    for (int k = 0; k < HID; k += 4) {
        float4 w0 = *(const float4*)(Wp + (k + 0) * HID);
        float4 w1 = *(const float4*)(Wp + (k + 1) * HID);
        float4 w2 = *(const float4*)(Wp + (k + 2) * HID);
        float4 w3 = *(const float4*)(Wp + (k + 3) * HID);
#pragma unroll
        for (int r = 0; r < 8; ++r) {
            float4 xv = *(const float4*)&Xrow[r * 132 + k];
            acc[r][0] += xv.x * w0.x + xv.y * w1.x + xv.z * w2.x + xv.w * w3.x;
            acc[r][1] += xv.x * w0.y + xv.y * w1.y + xv.z * w2.y + xv.w * w3.y;
            acc[r][2] += xv.x * w0.z + xv.y * w1.z + xv.z * w2.z + xv.w * w3.z;
            acc[r][3] += xv.x * w0.w + xv.y * w1.w + xv.z * w2.w + xv.w * w3.w;
        }
    }

    const float4 bb = *(const float4*)&b2[4 * cg];
    float2 w3v[4];
#pragma unroll
    for (int c = 0; c < 4; ++c)
        w3v[c] = *(const float2*)&W3[(4 * cg + c) * 2];
    const float b30 = b3[0], b31 = b3[1];

#pragma unroll
    for (int r = 0; r < 8; ++r) {
        float h0 = fmaxf(acc[r][0] + bb.x, 0.f);
        float h1 = fmaxf(acc[r][1] + bb.y, 0.f);
        float h2 = fmaxf(acc[r][2] + bb.z, 0.f);
        float h3 = fmaxf(acc[r][3] + bb.w, 0.f);
        float p0 = h0 * w3v[0].x + h1 * w3v[1].x + h2 * w3v[2].x + h3 * w3v[3].x;
        float p1 = h0 * w3v[0].y + h1 * w3v[1].y + h2 * w3v[2].y + h3 * w3v[3].y;
#pragma unroll
        for (int m = 1; m < 32; m <<= 1) {
            p0 += __shfl_xor(p0, m);
            p1 += __shfl_xor(p1, m);
        }
        long row = base + rg * 8 + r;
        if (cg == 0 && row < NN)
            ((float2*)out)[row] = make_float2(p0 + b30, p1 + b31);
    }
}

extern "C" void kernel_launch(void* const* d_in, const int* in_sizes, int n_in,
                              void* d_out, int out_size, void* d_ws, size_t ws_size,
                              hipStream_t stream) {
    const float* x   = (const float*)d_in[0];
    const int*   ei  = (const int*)d_in[1];
    const float* W1  = (const float*)d_in[2];
    const float* b1  = (const float*)d_in[3];
    const float* W2  = (const float*)d_in[4];
    const float* b2  = (const float*)d_in[5];
    const float* W3  = (const float*)d_in[6];
    const float* b3  = (const float*)d_in[7];
    float* out = (float*)d_out;

    const int* srcA = ei;
    const int* dstA = ei + NE;

    char* p = (char*)d_ws;
    auto alloc = [&](size_t bytes) {
        char* r = p;
        p += (bytes + 255) & ~(size_t)255;
        return r;
    };
    float* dinv   = (float*)alloc(NN * 4);
    int*   counts = (int*)  alloc(NN * 4);
    int*   rowptr = (int*)  alloc((NN + 1) * 4);
    int*   bsum   = (int*)  alloc(512 * 4);
    int*   col    = (int*)  alloc((size_t)NE * 4);
    float* bufA   = (float*)alloc((size_t)NN * HID * 4);   // h1, then g
    float* bufB   = (float*)alloc((size_t)NN * HID * 4);   // h2

    const int nb_n = (NN + 255) / 256;
    const int nb_e = (NE + 255) / 256;
    const int nb_g = (NN + 63) / 64;
    const int nb_agg = 8 * 2 * CHUNKS;      // 25008 blocks

    // ---- CSR build ----
    k_zero_counts<<<nb_n, 256, 0, stream>>>(counts);
    k_hist<<<nb_e, 256, 0, stream>>>(dstA, counts);
    k_dinv<<<nb_n, 256, 0, stream>>>(counts, dinv);
    k_scanA<<<nb_n, 256, 0, stream>>>(counts, rowptr, bsum);
    k_scanB<<<1, 512, 0, stream>>>(bsum, nb_n);
    k_scanC<<<nb_n, 256, 0, stream>>>(rowptr, bsum, counts);
    k_fill<<<nb_e, 256, 0, stream>>>(srcA, dstA, rowptr, counts, col);

    // ---- layer 1 GEMM -> h1 (sliced) ----
    k_gemm_sl<FIN, 168, false><<<nb_g, 256, 0, stream>>>(x, W1, bufA);

    // ---- agg1 + b1 + relu -> h2 (sliced) ----
    k_agg_px<true><<<nb_agg, 256, 0, stream>>>(bufA, rowptr, col, dinv, b1, bufB);

    // ---- agg2 (pure A-hat) -> g (sliced) ----
    k_agg_px<false><<<nb_agg, 256, 0, stream>>>(bufB, rowptr, col, dinv, nullptr, bufA);

    // ---- tail: relu(g @ W2 + b2) @ W3 + b3 ----
    k_tail<<<nb_g, 256, 0, stream>>>(bufA, W2, b2, W3, b3, out);
}

// Round 8
// 409.005 us; speedup vs baseline: 3.5667x; 2.7038x over previous
//
#include <hip/hip_runtime.h>
#include <hip/hip_fp16.h>

// EllipticGNN: 2-layer GCN + linear head, f32 compute.
// Gathered operands stored as fp16 rows PRE-SCALED by dinv[src]:
//   agg_i = dinv_i * (hhat_i + sum_s hhat_s),  hhat_s = dinv_s * h_s
// -> no wv stream, 256B rows (2 cache lines/edge), 25.6MB working set.

constexpr int NN   = 100000;
constexpr int NE   = 1600000;
constexpr int FIN  = 165;
constexpr int HID  = 128;

__global__ __launch_bounds__(256) void k_zero_counts(int* __restrict__ c) {
    int i = blockIdx.x * 256 + threadIdx.x;
    if (i < NN) c[i] = 0;
}

__global__ __launch_bounds__(256) void k_hist(const int* __restrict__ dst,
                                              int* __restrict__ c) {
    int i = blockIdx.x * 256 + threadIdx.x;
    if (i < NE) atomicAdd(&c[dst[i]], 1);
}

__global__ __launch_bounds__(256) void k_dinv(const int* __restrict__ c,
                                              float* __restrict__ dinv) {
    int i = blockIdx.x * 256 + threadIdx.x;
    if (i < NN) dinv[i] = rsqrtf((float)c[i] + 1.0f);   // +1 self-loop
}

__global__ __launch_bounds__(256) void k_scanA(const int* __restrict__ c,
                                               int* __restrict__ rowptr,
                                               int* __restrict__ bsum) {
    __shared__ int s[256];
    int t = threadIdx.x;
    int i = blockIdx.x * 256 + t;
    int v = (i < NN) ? c[i] : 0;
    s[t] = v; __syncthreads();
    for (int off = 1; off < 256; off <<= 1) {
        int add = (t >= off) ? s[t - off] : 0;
        __syncthreads();
        s[t] += add;
        __syncthreads();
    }
    if (i < NN) rowptr[i] = s[t] - v;
    if (t == 255) bsum[blockIdx.x] = s[255];
}

__global__ __launch_bounds__(512) void k_scanB(int* __restrict__ bsum, int nb) {
    __shared__ int s[512];
    int t = threadIdx.x;
    int v = (t < nb) ? bsum[t] : 0;
    s[t] = v; __syncthreads();
    for (int off = 1; off < 512; off <<= 1) {
        int add = (t >= off) ? s[t - off] : 0;
        __syncthreads();
        s[t] += add;
        __syncthreads();
    }
    if (t < nb) bsum[t] = s[t] - v;
}

__global__ __launch_bounds__(256) void k_scanC(int* __restrict__ rowptr,
                                               const int* __restrict__ bsum,
                                               int* __restrict__ c) {
    int i = blockIdx.x * 256 + threadIdx.x;
    if (i < NN) { rowptr[i] += bsum[blockIdx.x]; c[i] = 0; }
    if (i == 0) rowptr[NN] = NE;
}

__global__ __launch_bounds__(256) void k_fill(const int* __restrict__ src,
                                              const int* __restrict__ dst,
                                              const int* __restrict__ rowptr,
                                              int* __restrict__ cur,
                                              int* __restrict__ col) {
    int e = blockIdx.x * 256 + threadIdx.x;
    if (e >= NE) return;
    int s = src[e], d = dst[e];
    int pos = rowptr[d] + atomicAdd(&cur[d], 1);
    col[pos] = s;
}

// Tiled GEMM: Yh[row][c] = fp16( dinv[row] * (X[row] @ W)[c] ).
template<int K, int KP, bool VEC4>
__global__ __launch_bounds__(256) void k_gemm_h(const float* __restrict__ X,
                                                const float* __restrict__ W,
                                                const float* __restrict__ dinv,
                                                __half* __restrict__ Yh) {
    __shared__ float Xs[64 * KP];
    const int tid = threadIdx.x;
    const long base = (long)blockIdx.x * 64;
    const int rows = (NN - base < 64) ? (int)(NN - base) : 64;

    if (VEC4) {
        const float4* Xg = (const float4*)(X + base * K);
        const int tot4 = rows * (K / 4);
        for (int i = tid; i < tot4; i += 256) {
            int r = i / (K / 4), c4 = i % (K / 4);
            *(float4*)&Xs[r * KP + c4 * 4] = Xg[i];
        }
    } else {
        const int tot = rows * K;
        const float* Xg = X + base * K;
        for (int i = tid; i < tot; i += 256) {
            int r = i / K, c = i % K;
            Xs[r * KP + c] = Xg[i];
        }
    }
    __syncthreads();

    const int cg = tid & 31;
    const int rg = tid >> 5;
    const float* Wp = W + 4 * cg;
    const float* Xrow = &Xs[rg * 8 * KP];

    float acc[8][4];
#pragma unroll
    for (int r = 0; r < 8; ++r)
#pragma unroll
        for (int c = 0; c < 4; ++c) acc[r][c] = 0.0f;

    int k = 0;
    for (; k + 4 <= K; k += 4) {
        float4 w0 = *(const float4*)(Wp + (k + 0) * HID);
        float4 w1 = *(const float4*)(Wp + (k + 1) * HID);
        float4 w2 = *(const float4*)(Wp + (k + 2) * HID);
        float4 w3 = *(const float4*)(Wp + (k + 3) * HID);
#pragma unroll
        for (int r = 0; r < 8; ++r) {
            float4 xv = *(const float4*)&Xrow[r * KP + k];
            acc[r][0] += xv.x * w0.x + xv.y * w1.x + xv.z * w2.x + xv.w * w3.x;
            acc[r][1] += xv.x * w0.y + xv.y * w1.y + xv.z * w2.y + xv.w * w3.y;
            acc[r][2] += xv.x * w0.z + xv.y * w1.z + xv.z * w2.z + xv.w * w3.z;
            acc[r][3] += xv.x * w0.w + xv.y * w1.w + xv.z * w2.w + xv.w * w3.w;
        }
    }
    for (; k < K; ++k) {
        float4 wt = *(const float4*)(Wp + k * HID);
#pragma unroll
        for (int r = 0; r < 8; ++r) {
            float xs = Xrow[r * KP + k];
            acc[r][0] += xs * wt.x;
            acc[r][1] += xs * wt.y;
            acc[r][2] += xs * wt.z;
            acc[r][3] += xs * wt.w;
        }
    }

#pragma unroll
    for (int r = 0; r < 8; ++r) {
        long row = base + rg * 8 + r;
        if (row < NN) {
            float d = dinv[row];
            __half2 p0 = __floats2half2_rn(acc[r][0] * d, acc[r][1] * d);
            __half2 p1 = __floats2half2_rn(acc[r][2] * d, acc[r][3] * d);
            uint2 uv;
            uv.x = *reinterpret_cast<unsigned int*>(&p0);
            uv.y = *reinterpret_cast<unsigned int*>(&p1);
            *reinterpret_cast<uint2*>(&Yh[row * HID + 4 * cg]) = uv;
        }
    }
}

// Gather sum of pre-scaled fp16 rows (incl. self) for node i; lane j owns
// cols {2j,2j+1}. Returns f32 accumulators.
__device__ __forceinline__ void gather_row_h(const __half2* __restrict__ H2,
                                             const int* __restrict__ rowptr,
                                             const int* __restrict__ col,
                                             int i, int j,
                                             float& a0, float& a1) {
    int k = rowptr[i];
    const int end = rowptr[i + 1];
    float2 self = __half22float2(H2[(size_t)i * 64 + j]);
    a0 = self.x;
    a1 = self.y;
    for (; k + 8 <= end; k += 8) {
        int s[8];
#pragma unroll
        for (int u = 0; u < 8; ++u)
            s[u] = __builtin_nontemporal_load(&col[k + u]);
        __half2 h[8];
#pragma unroll
        for (int u = 0; u < 8; ++u) h[u] = H2[(size_t)s[u] * 64 + j];
#pragma unroll
        for (int u = 0; u < 8; ++u) {
            float2 f = __half22float2(h[u]);
            a0 += f.x;
            a1 += f.y;
        }
    }
    for (; k < end; ++k) {
        int cs = __builtin_nontemporal_load(&col[k]);
        float2 f = __half22float2(H2[(size_t)cs * 64 + j]);
        a0 += f.x;
        a1 += f.y;
    }
}

// aggA: one wave per 8 nodes. Per node: gather hhat -> h2 = relu(di*acc+b1)
// -> LDS. Then mini-GEMM (8x128)xW2, epilogue pre-scales by di and stores
// fp16 qhat.
__global__ __launch_bounds__(64) void k_aggA(const __half* __restrict__ Hh,
                                             const int* __restrict__ rowptr,
                                             const int* __restrict__ col,
                                             const float* __restrict__ dinv,
                                             const float* __restrict__ b1,
                                             const float* __restrict__ W2,
                                             __half* __restrict__ Qh) {
    __shared__ float vlds[8 * 128];
    const int j = threadIdx.x;                    // 0..63
    const int base = blockIdx.x * 8;
    const __half2* H2 = (const __half2*)Hh;
    const float2 bb = ((const float2*)b1)[j];

    float dloc[8];
#pragma unroll
    for (int n = 0; n < 8; ++n) dloc[n] = dinv[base + n];

#pragma unroll
    for (int n = 0; n < 8; ++n) {
        const int i = base + n;
        const float di = dloc[n];
        float a0, a1;
        gather_row_h(H2, rowptr, col, i, j, a0, a1);
        float r0 = fmaxf(di * a0 + bb.x, 0.0f);
        float r1 = fmaxf(di * a1 + bb.y, 0.0f);
        *(float2*)&vlds[n * 128 + 2 * j] = make_float2(r0, r1);
    }
    __syncthreads();

    // q[n][2j,2j+1] = sum_k vlds[n][k] * W2[k][2j,2j+1]; store fp16(di*q)
    float2 acc[8];
#pragma unroll
    for (int n = 0; n < 8; ++n) acc[n] = make_float2(0.f, 0.f);
    const float* Wp = W2 + 2 * j;
    for (int k4 = 0; k4 < 32; ++k4) {
        float2 w0 = *(const float2*)(Wp + (k4 * 4 + 0) * HID);
        float2 w1 = *(const float2*)(Wp + (k4 * 4 + 1) * HID);
        float2 w2 = *(const float2*)(Wp + (k4 * 4 + 2) * HID);
        float2 w3 = *(const float2*)(Wp + (k4 * 4 + 3) * HID);
#pragma unroll
        for (int n = 0; n < 8; ++n) {
            float4 v = *(const float4*)&vlds[n * 128 + k4 * 4];  // broadcast
            acc[n].x += v.x * w0.x + v.y * w1.x + v.z * w2.x + v.w * w3.x;
            acc[n].y += v.x * w0.y + v.y * w1.y + v.z * w2.y + v.w * w3.y;
        }
    }
#pragma unroll
    for (int n = 0; n < 8; ++n) {
        __half2 p = __floats2half2_rn(acc[n].x * dloc[n], acc[n].y * dloc[n]);
        ((__half2*)Qh)[(size_t)(base + n) * 64 + j] = p;
    }
}

// aggB: one wave per 4 nodes. Gather qhat, g = relu(di*acc+b2), head inline.
__global__ __launch_bounds__(64) void k_aggB(const __half* __restrict__ Qh,
                                             const int* __restrict__ rowptr,
                                             const int* __restrict__ col,
                                             const float* __restrict__ dinv,
                                             const float* __restrict__ b2,
                                             const float* __restrict__ W3,
                                             const float* __restrict__ b3,
                                             float* __restrict__ out) {
    const int j = threadIdx.x;
    const int base = blockIdx.x * 4;
    const __half2* Q2 = (const __half2*)Qh;
    const float2 bb = ((const float2*)b2)[j];
    // W3 rows 2j, 2j+1, both cols
    const float4 w3v = *(const float4*)&W3[2 * j * 2];
    const float b30 = b3[0], b31 = b3[1];

#pragma unroll
    for (int n = 0; n < 4; ++n) {
        const int i = base + n;
        const float di = dinv[i];
        float a0, a1;
        gather_row_h(Q2, rowptr, col, i, j, a0, a1);
        float r0 = fmaxf(di * a0 + bb.x, 0.0f);
        float r1 = fmaxf(di * a1 + bb.y, 0.0f);
        float p0 = r0 * w3v.x + r1 * w3v.z;
        float p1 = r0 * w3v.y + r1 * w3v.w;
#pragma unroll
        for (int m = 1; m < 64; m <<= 1) {
            p0 += __shfl_xor(p0, m);
            p1 += __shfl_xor(p1, m);
        }
        if (j == 0)
            ((float2*)out)[i] = make_float2(p0 + b30, p1 + b31);
    }
}

extern "C" void kernel_launch(void* const* d_in, const int* in_sizes, int n_in,
                              void* d_out, int out_size, void* d_ws, size_t ws_size,
                              hipStream_t stream) {
    const float* x   = (const float*)d_in[0];
    const int*   ei  = (const int*)d_in[1];
    const float* W1  = (const float*)d_in[2];
    const float* b1  = (const float*)d_in[3];
    const float* W2  = (const float*)d_in[4];
    const float* b2  = (const float*)d_in[5];
    const float* W3  = (const float*)d_in[6];
    const float* b3  = (const float*)d_in[7];
    float* out = (float*)d_out;

    const int* srcA = ei;
    const int* dstA = ei + NE;

    char* p = (char*)d_ws;
    auto alloc = [&](size_t bytes) {
        char* r = p;
        p += (bytes + 255) & ~(size_t)255;
        return r;
    };
    float*  dinv   = (float*)alloc(NN * 4);
    int*    counts = (int*)  alloc(NN * 4);
    int*    rowptr = (int*)  alloc((NN + 1) * 4);
    int*    bsum   = (int*)  alloc(512 * 4);
    int*    col    = (int*)  alloc((size_t)NE * 4);
    __half* hhat   = (__half*)alloc((size_t)NN * HID * 2);   // dinv*h1, fp16
    __half* qhat   = (__half*)alloc((size_t)NN * HID * 2);   // dinv*q,  fp16

    const int nb_n = (NN + 255) / 256;
    const int nb_e = (NE + 255) / 256;
    const int nb_g = (NN + 63) / 64;

    // ---- CSR build ----
    k_zero_counts<<<nb_n, 256, 0, stream>>>(counts);
    k_hist<<<nb_e, 256, 0, stream>>>(dstA, counts);
    k_dinv<<<nb_n, 256, 0, stream>>>(counts, dinv);
    k_scanA<<<nb_n, 256, 0, stream>>>(counts, rowptr, bsum);
    k_scanB<<<1, 512, 0, stream>>>(bsum, nb_n);
    k_scanC<<<nb_n, 256, 0, stream>>>(rowptr, bsum, counts);
    k_fill<<<nb_e, 256, 0, stream>>>(srcA, dstA, rowptr, counts, col);

    // ---- layer 1 GEMM -> hhat (fp16, pre-scaled) ----
    k_gemm_h<FIN, 168, false><<<nb_g, 256, 0, stream>>>(x, W1, dinv, hhat);

    // ---- agg1 + b1 + relu + GEMV W2 -> qhat ----  (NN = 8 * 12500)
    k_aggA<<<NN / 8, 64, 0, stream>>>(hhat, rowptr, col, dinv, b1, W2, qhat);

    // ---- agg2 + b2 + relu + head -> out ----      (NN = 4 * 25000)
    k_aggB<<<NN / 4, 64, 0, stream>>>(qhat, rowptr, col, dinv, b2, W3, b3, out);
}